// Round 3
// baseline (88587.433 us; speedup 1.0000x reference)
//
#include <hip/hip_runtime.h>
#include <math.h>

typedef unsigned short u16;
typedef __attribute__((ext_vector_type(8))) short s16x8;
typedef __attribute__((ext_vector_type(4))) float f4v;

__device__ __forceinline__ float bf2f(short u) {
    union { unsigned int i; float f; } v;
    v.i = ((unsigned int)(u16)u) << 16;
    return v.f;
}
__device__ __forceinline__ u16 f2bf(float f) {
    union { float f; unsigned int i; } v; v.f = f;
    unsigned int x = v.i;
    return (u16)((x + 0x7FFFu + ((x >> 16) & 1u)) >> 16);
}

// 3 fp32 weight rows vs one LDS h row (fp32), interleaved for ILP
__device__ __forceinline__ void gemv3_f32(const float* __restrict__ w0,
                                          const float* __restrict__ w1,
                                          const float* __restrict__ w2,
                                          const f4v* __restrict__ hv,
                                          int n4, float& a0, float& a1, float& a2)
{
    for (int k = 0; k < n4; ++k) {
        f4v h4 = hv[k];
        f4v x0 = *(const f4v*)(w0 + k * 4);
        f4v x1 = *(const f4v*)(w1 + k * 4);
        f4v x2 = *(const f4v*)(w2 + k * 4);
        a0 += h4[0]*x0[0] + h4[1]*x0[1] + h4[2]*x0[2] + h4[3]*x0[3];
        a1 += h4[0]*x1[0] + h4[1]*x1[1] + h4[2]*x1[2] + h4[3]*x1[3];
        a2 += h4[0]*x2[0] + h4[1]*x2[1] + h4[2]*x2[2] + h4[3]*x2[3];
    }
}

__device__ __forceinline__ float dot_w32_v32(const float* __restrict__ w,
                                             const float* __restrict__ v, int n)
{
    float a = 0.f;
    for (int k = 0; k < n; ++k) a += w[k] * v[k];
    return a;
}
__device__ __forceinline__ float dot_w32_vbf(const float* __restrict__ w,
                                             const u16* __restrict__ v, int n8)
{
    float a = 0.f;
    for (int k8 = 0; k8 < n8; ++k8) {
        s16x8 v8 = *(const s16x8*)(v + k8 * 8);
        f4v w0 = *(const f4v*)(w + k8 * 8);
        f4v w1 = *(const f4v*)(w + k8 * 8 + 4);
        a += w0[0]*bf2f(v8[0]) + w0[1]*bf2f(v8[1]) + w0[2]*bf2f(v8[2]) + w0[3]*bf2f(v8[3])
           + w1[0]*bf2f(v8[4]) + w1[1]*bf2f(v8[5]) + w1[2]*bf2f(v8[6]) + w1[3]*bf2f(v8[7]);
    }
    return a;
}

// ---------------- layer0 input gates: xg = x @ Wih0^T + bih, K=75, fp32 in, bf16 out ----------------
__global__ __launch_bounds__(256)
void xg0_kernel(const float* __restrict__ x,     // [6400][75]
                const float* __restrict__ Wih0,  // [2][3072][75]
                const float* __restrict__ b0,    // [2][2][3072]
                u16* __restrict__ xg)            // [2][6400][3072]
{
    const int bt0 = blockIdx.x * 16;
    const int dir = blockIdx.y;
    __shared__ float xl[16][76];
    for (int idx = threadIdx.x; idx < 16 * 75; idx += 256) {
        int r = idx / 75, k = idx % 75;
        xl[r][k] = x[(size_t)(bt0 + r) * 75 + k];
    }
    __syncthreads();
    const float* W = Wih0 + (size_t)dir * 3072 * 75;
    const float* bih = b0 + (size_t)dir * 6144;
    for (int i = 0; i < 12; ++i) {
        int g = threadIdx.x + i * 256;
        const float* wr = W + (size_t)g * 75;
        float bv = bih[g];
        float acc[16];
#pragma unroll
        for (int r = 0; r < 16; ++r) acc[r] = bv;
        for (int k = 0; k < 75; ++k) {
            float w = wr[k];
#pragma unroll
            for (int r = 0; r < 16; ++r) acc[r] += xl[r][k] * w;
        }
#pragma unroll
        for (int r = 0; r < 16; ++r)
            xg[((size_t)dir * 6400 + bt0 + r) * 3072 + g] = f2bf(acc[r]);
    }
}

// ---------------- MFMA bt-GEMM: C[6400,3072] = A(bf16)[6400,K] @ B(fp32)[3072,K]^T + bias ----------------
__global__ __launch_bounds__(256)
void xg_gemm(const u16* __restrict__ A, const float* __restrict__ Bm,
             const float* __restrict__ bias, u16* __restrict__ C, int K)
{
    __shared__ u16 Alds[64 * 40];
    __shared__ u16 Blds[64 * 40];
    const int m0 = blockIdx.x * 64;
    const int n0 = blockIdx.y * 64;
    const int wave = threadIdx.x >> 6;
    const int lane = threadIdx.x & 63;
    const int r = threadIdx.x >> 2;           // 0..63 staging row
    const int kk = (threadIdx.x & 3) * 8;     // 0,8,16,24
    const int mrow = wave * 16 + (lane & 15);
    const int kq = (lane >> 4) * 8;
    f4v acc[4];
#pragma unroll
    for (int nt = 0; nt < 4; ++nt) acc[nt] = (f4v){0.f, 0.f, 0.f, 0.f};

    for (int k0 = 0; k0 < K; k0 += 32) {
        *(s16x8*)&Alds[r * 40 + kk] = *(const s16x8*)(A + (size_t)(m0 + r) * K + k0 + kk);
        f4v b0v = *(const f4v*)(Bm + (size_t)(n0 + r) * K + k0 + kk);
        f4v b1v = *(const f4v*)(Bm + (size_t)(n0 + r) * K + k0 + kk + 4);
        s16x8 bb;
#pragma unroll
        for (int i = 0; i < 4; ++i) { bb[i] = (short)f2bf(b0v[i]); bb[4 + i] = (short)f2bf(b1v[i]); }
        *(s16x8*)&Blds[r * 40 + kk] = bb;
        __syncthreads();
        s16x8 a = *(const s16x8*)&Alds[mrow * 40 + kq];
#pragma unroll
        for (int nt = 0; nt < 4; ++nt) {
            s16x8 b = *(const s16x8*)&Blds[(nt * 16 + (lane & 15)) * 40 + kq];
            acc[nt] = __builtin_amdgcn_mfma_f32_16x16x32_bf16(a, b, acc[nt], 0, 0, 0);
        }
        __syncthreads();
    }
    const int col = lane & 15;
    const int rq = (lane >> 4) * 4;
#pragma unroll
    for (int nt = 0; nt < 4; ++nt) {
        int n = n0 + nt * 16 + col;
        float bbv = bias[n];
#pragma unroll
        for (int rg = 0; rg < 4; ++rg) {
            int m = m0 + wave * 16 + rq + rg;
            C[(size_t)m * 3072 + n] = f2bf(acc[nt][rg] + bbv);
        }
    }
}

// ---------------- encoder scan step (one t, both dirs), xg precomputed ----------------
__global__ __launch_bounds__(512)
void enc_scan_step(int t,
                   const float* __restrict__ h_in,   // [2][64][1024] fp32
                   float* __restrict__ h_out,
                   const float* __restrict__ Whh, size_t whh_dir_stride,   // [3072][1024] per dir
                   const float* __restrict__ bias, int bias_dir_stride,    // [2][3072] per dir
                   const u16* __restrict__ xg, size_t xg_dir_stride,       // [6400][3072] per dir
                   u16* __restrict__ y)              // [6400][2048] bf16
{
    const int dir = blockIdx.z;
    const int jt = blockIdx.x;        // 0..31
    const int b0 = blockIdx.y * 16;   // 0..3 * 16
    __shared__ float hlds[16][1024];  // 64 KB
    const float* hin = h_in + (size_t)dir * 65536 + (size_t)b0 * 1024;
    if (t == 0) {
        f4v z = {0.f, 0.f, 0.f, 0.f};
        for (int idx = threadIdx.x; idx < 4096; idx += 512) ((f4v*)hlds)[idx] = z;
    } else {
        for (int idx = threadIdx.x; idx < 4096; idx += 512)
            ((f4v*)hlds)[idx] = ((const f4v*)hin)[idx];
    }
    __syncthreads();
    const int jl = threadIdx.x & 31;
    const int j  = jt * 32 + jl;
    const int bp = threadIdx.x >> 5;  // 0..15
    const float* wd = Whh + (size_t)dir * whh_dir_stride;
    float a0 = 0.f, a1 = 0.f, a2 = 0.f;
    gemv3_f32(wd + (size_t)j * 1024, wd + (size_t)(1024 + j) * 1024,
              wd + (size_t)(2048 + j) * 1024, (const f4v*)&hlds[bp][0], 256, a0, a1, a2);
    const float* bhh = bias + dir * bias_dir_stride + 3072;
    const int gb = b0 + bp;
    const u16* xr = xg + (size_t)dir * xg_dir_stride + ((size_t)gb * 100 + t) * 3072;
    float pr = bf2f((short)xr[j]) + a0 + bhh[j];
    float pz = bf2f((short)xr[1024 + j]) + a1 + bhh[1024 + j];
    float pn = bf2f((short)xr[2048 + j]);
    float rg = 1.f / (1.f + expf(-pr));
    float zg = 1.f / (1.f + expf(-pz));
    float ng = tanhf(pn + rg * (a2 + bhh[2048 + j]));
    float hold = hlds[bp][j];
    float hnew = (1.f - zg) * ng + zg * hold;
    h_out[(size_t)dir * 65536 + (size_t)gb * 1024 + j] = hnew;
    y[((size_t)gb * 100 + t) * 2048 + (size_t)dir * 1024 + j] = f2bf(hnew);
}

// ---------------- encoder scan step, FUSED input gates (low-ws fallback) ----------------
__global__ __launch_bounds__(512)
void enc_scan_fused(int t,
                    const float* __restrict__ h_in, float* __restrict__ h_out,
                    const float* __restrict__ Whh, size_t whh_stride,
                    const float* __restrict__ Wih, size_t wih_stride, int Kin,
                    const float* __restrict__ xf, const u16* __restrict__ xb,
                    const float* __restrict__ bias, int bias_stride,
                    u16* __restrict__ y)
{
    const int dir = blockIdx.z;
    const int jt = blockIdx.x;
    const int b0 = blockIdx.y * 16;
    __shared__ float hlds[16][1024];
    const float* hin = h_in + (size_t)dir * 65536 + (size_t)b0 * 1024;
    if (t == 0) {
        f4v z = {0.f, 0.f, 0.f, 0.f};
        for (int idx = threadIdx.x; idx < 4096; idx += 512) ((f4v*)hlds)[idx] = z;
    } else {
        for (int idx = threadIdx.x; idx < 4096; idx += 512)
            ((f4v*)hlds)[idx] = ((const f4v*)hin)[idx];
    }
    __syncthreads();
    const int jl = threadIdx.x & 31;
    const int j  = jt * 32 + jl;
    const int bp = threadIdx.x >> 5;
    const float* wd = Whh + (size_t)dir * whh_stride;
    float a0 = 0.f, a1 = 0.f, a2 = 0.f;
    gemv3_f32(wd + (size_t)j * 1024, wd + (size_t)(1024 + j) * 1024,
              wd + (size_t)(2048 + j) * 1024, (const f4v*)&hlds[bp][0], 256, a0, a1, a2);
    const float* bd = bias + dir * bias_stride;
    const float* wi = Wih + (size_t)dir * wih_stride;
    const int gb = b0 + bp;
    float gi[3];
#pragma unroll
    for (int g = 0; g < 3; ++g) {
        const float* wr = wi + (size_t)(g * 1024 + j) * Kin;
        float s;
        if (xf) s = dot_w32_v32(wr, xf + ((size_t)gb * 100 + t) * Kin, Kin);
        else    s = dot_w32_vbf(wr, xb + ((size_t)gb * 100 + t) * Kin, Kin >> 3);
        gi[g] = bd[g * 1024 + j] + s;
    }
    const float* bhh = bd + 3072;
    float pr = gi[0] + a0 + bhh[j];
    float pz = gi[1] + a1 + bhh[1024 + j];
    float rg = 1.f / (1.f + expf(-pr));
    float zg = 1.f / (1.f + expf(-pz));
    float ng = tanhf(gi[2] + rg * (a2 + bhh[2048 + j]));
    float hold = hlds[bp][j];
    float hnew = (1.f - zg) * ng + zg * hold;
    h_out[(size_t)dir * 65536 + (size_t)gb * 1024 + j] = hnew;
    y[((size_t)gb * 100 + t) * 2048 + (size_t)dir * 1024 + j] = f2bf(hnew);
}

// ---------------- gather enc_hidden = y[b, sl-1] ----------------
__global__ __launch_bounds__(256)
void gather_kernel(const int* __restrict__ seq_len, const u16* __restrict__ y,
                   float* __restrict__ out_enc, float* __restrict__ h_dec)
{
    int idx = blockIdx.x * 256 + threadIdx.x;   // < 131072
    int b = idx >> 11, j = idx & 2047;
    int sl = seq_len[b];
    sl = sl < 1 ? 1 : (sl > 100 ? 100 : sl);
    float v = bf2f((short)y[((size_t)b * 100 + (sl - 1)) * 2048 + j]);
    out_enc[idx] = v;
    h_dec[idx] = v;
}

// ---------------- decoder scan step, H=K=2048, input gates constant = dec_b[0] ----------------
__global__ __launch_bounds__(512)
void dec_scan_step(int t, const float* __restrict__ h_in, float* __restrict__ h_out,
                   const float* __restrict__ Whh,  // [6144][2048] fp32
                   const float* __restrict__ db,   // [2][6144] fp32
                   u16* __restrict__ ys)           // [6400][2048] bf16
{
    const int jt = blockIdx.x;       // 0..63
    const int b0 = blockIdx.y * 16;  // 0..3 * 16
    __shared__ float hlds[16][1024];
    const int jl = threadIdx.x & 31;
    const int j  = jt * 32 + jl;
    const int bp = threadIdx.x >> 5;
    float a0 = 0.f, a1 = 0.f, a2 = 0.f;
    float hold = 0.f;
    for (int kc = 0; kc < 2; ++kc) {
        for (int idx = threadIdx.x; idx < 4096; idx += 512) {
            int rr = idx >> 8, cc = idx & 255;
            ((f4v*)hlds)[idx] = *(const f4v*)(h_in + (size_t)(b0 + rr) * 2048 + kc * 1024 + cc * 4);
        }
        __syncthreads();
        if ((j >> 10) == kc) hold = hlds[bp][j & 1023];
        const float* wb = Whh + kc * 1024;
        gemv3_f32(wb + (size_t)j * 2048, wb + (size_t)(2048 + j) * 2048,
                  wb + (size_t)(4096 + j) * 2048, (const f4v*)&hlds[bp][0], 256, a0, a1, a2);
        __syncthreads();
    }
    const int gb = b0 + bp;
    float pr = db[j] + a0 + db[6144 + j];
    float pz = db[2048 + j] + a1 + db[6144 + 2048 + j];
    float rg = 1.f / (1.f + expf(-pr));
    float zg = 1.f / (1.f + expf(-pz));
    float ng = tanhf(db[4096 + j] + rg * (a2 + db[6144 + 4096 + j]));
    float hnew = (1.f - zg) * ng + zg * hold;
    h_out[(size_t)gb * 2048 + j] = hnew;
    ys[((size_t)gb * 100 + t) * 2048 + j] = f2bf(hnew);
}

// ---------------- output projection: dec_out[6400,75] = ys @ out_W^T + out_b ----------------
__global__ __launch_bounds__(256)
void proj_kernel(const u16* __restrict__ ys, const float* __restrict__ oW,
                 const float* __restrict__ oB, float* __restrict__ dec_out)
{
    const int r0 = blockIdx.x * 8;   // 800 blocks
    __shared__ float yl[8][2048];    // 64 KB
    __shared__ float psum[3][8][76];
    for (int idx = threadIdx.x; idx < 2048; idx += 256) {
        int rr = idx >> 8, cc = idx & 255;
        s16x8 v = ((const s16x8*)(ys + (size_t)(r0 + rr) * 2048))[cc];
#pragma unroll
        for (int i = 0; i < 8; ++i) yl[rr][cc * 8 + i] = bf2f(v[i]);
    }
    __syncthreads();
    if (threadIdx.x < 225) {
        int d = threadIdx.x % 75, seg = threadIdx.x / 75;
        int ks = seg * 683, ke = ks + 683 < 2048 ? ks + 683 : 2048;
        const float* wr = oW + (size_t)d * 2048;
        float acc[8] = {0.f, 0.f, 0.f, 0.f, 0.f, 0.f, 0.f, 0.f};
        for (int k = ks; k < ke; ++k) {
            float w = wr[k];
#pragma unroll
            for (int r = 0; r < 8; ++r) acc[r] += yl[r][k] * w;
        }
#pragma unroll
        for (int r = 0; r < 8; ++r) psum[seg][r][d] = acc[r];
    }
    __syncthreads();
    for (int idx = threadIdx.x; idx < 600; idx += 256) {
        int r = idx / 75, d = idx % 75;
        dec_out[(size_t)(r0 + r) * 75 + d] =
            psum[0][r][d] + psum[1][r][d] + psum[2][r][d] + oB[d];
    }
}

extern "C" void kernel_launch(void* const* d_in, const int* in_sizes, int n_in,
                              void* d_out, int out_size, void* d_ws, size_t ws_size,
                              hipStream_t stream)
{
    const float* x    = (const float*)d_in[0];
    const int*   sl   = (const int*)d_in[1];
    const float* Wih0 = (const float*)d_in[2];
    const float* Whh0 = (const float*)d_in[3];
    const float* b0   = (const float*)d_in[4];
    const float* Wih  = (const float*)d_in[5];
    const float* Whh  = (const float*)d_in[6];
    const float* bE   = (const float*)d_in[7];
    const float* dWhh = (const float*)d_in[9];
    const float* dB   = (const float*)d_in[10];
    const float* oW   = (const float*)d_in[11];
    const float* oB   = (const float*)d_in[12];
    float* out_enc = (float*)d_out;            // [64][2048] fp32
    float* dec_out = (float*)d_out + 131072;   // [64][100][75] fp32

    const size_t XG_B = 78643200;   // 2*6400*3072*2 (bf16)
    const size_t Y_B  = 26214400;   // 6400*2048*2 (bf16)
    const size_t HE_B = 1048576;    // 2*2*64*1024*4 (fp32 ping-pong)
    const size_t HD_B = 1048576;    // 2*64*2048*4
    const size_t FAST_NEED = XG_B + Y_B + HE_B + HD_B;   // ~102 MiB
    char* ws = (char*)d_ws;
    dim3 blk256(256), blk512(512);

    if (ws_size >= FAST_NEED) {
        u16*   xg = (u16*)ws;
        u16*   y  = (u16*)(ws + XG_B);
        float* hE = (float*)(ws + XG_B + Y_B);
        float* hD = (float*)(ws + XG_B + Y_B + HE_B);

        xg0_kernel<<<dim3(400, 2), blk256, 0, stream>>>(x, Wih0, b0, xg);
        for (int t = 0; t < 100; ++t) {
            int pp = t & 1;
            enc_scan_step<<<dim3(32, 4, 2), blk512, 0, stream>>>(
                t, hE + (size_t)pp * 131072, hE + (size_t)(pp ^ 1) * 131072,
                Whh0, (size_t)3072 * 1024, b0, 6144, xg, (size_t)19660800, y);
        }
        for (int l = 0; l < 2; ++l) {
            for (int d = 0; d < 2; ++d)
                xg_gemm<<<dim3(100, 48), blk256, 0, stream>>>(
                    y, Wih + (size_t)(l * 2 + d) * 3072 * 2048,
                    bE + (size_t)l * 12288 + (size_t)d * 6144,
                    xg + (size_t)d * 19660800, 2048);
            for (int t = 0; t < 100; ++t) {
                int pp = t & 1;
                enc_scan_step<<<dim3(32, 4, 2), blk512, 0, stream>>>(
                    t, hE + (size_t)pp * 131072, hE + (size_t)(pp ^ 1) * 131072,
                    Whh + (size_t)l * 2 * 3072 * 1024, (size_t)3072 * 1024,
                    bE + (size_t)l * 12288, 6144, xg, (size_t)19660800, y);
            }
        }
        gather_kernel<<<dim3(512), blk256, 0, stream>>>(sl, y, out_enc, hD);
        for (int t = 0; t < 100; ++t) {
            int pp = t & 1;
            dec_scan_step<<<dim3(64, 4), blk512, 0, stream>>>(
                t, hD + (size_t)pp * 131072, hD + (size_t)(pp ^ 1) * 131072, dWhh, dB, y);
        }
        proj_kernel<<<dim3(800), blk256, 0, stream>>>(y, oW, oB, dec_out);
    } else {
        // -------- fallback: fused input gates, double-buffered y (~52 MiB) --------
        u16*   y_a = (u16*)ws;
        u16*   y_b = (u16*)(ws + Y_B);
        float* hE  = (float*)(ws + 2 * Y_B);
        float* hD  = (float*)(ws + 2 * Y_B + HE_B);

        for (int t = 0; t < 100; ++t) {
            int pp = t & 1;
            enc_scan_fused<<<dim3(32, 4, 2), blk512, 0, stream>>>(
                t, hE + (size_t)pp * 131072, hE + (size_t)(pp ^ 1) * 131072,
                Whh0, (size_t)3072 * 1024, Wih0, (size_t)3072 * 75, 75, x, (const u16*)0,
                b0, 6144, y_a);
        }
        for (int l = 0; l < 2; ++l) {
            const u16* yin = (l == 0) ? y_a : y_b;
            u16* yout      = (l == 0) ? y_b : y_a;
            for (int t = 0; t < 100; ++t) {
                int pp = t & 1;
                enc_scan_fused<<<dim3(32, 4, 2), blk512, 0, stream>>>(
                    t, hE + (size_t)pp * 131072, hE + (size_t)(pp ^ 1) * 131072,
                    Whh + (size_t)l * 2 * 3072 * 1024, (size_t)3072 * 1024,
                    Wih + (size_t)l * 2 * 3072 * 2048, (size_t)3072 * 2048, 2048,
                    (const float*)0, yin, bE + (size_t)l * 12288, 6144, yout);
            }
        }
        gather_kernel<<<dim3(512), blk256, 0, stream>>>(sl, y_a, out_enc, hD);
        for (int t = 0; t < 100; ++t) {
            int pp = t & 1;
            dec_scan_step<<<dim3(64, 4), blk512, 0, stream>>>(
                t, hD + (size_t)pp * 131072, hD + (size_t)(pp ^ 1) * 131072, dWhh, dB, y_b);
        }
        proj_kernel<<<dim3(800), blk256, 0, stream>>>(y_b, oW, oB, dec_out);
    }
}

// Round 4
// 21585.767 us; speedup vs baseline: 4.1040x; 4.1040x over previous
//
#include <hip/hip_runtime.h>
#include <math.h>

typedef unsigned short u16;
typedef __attribute__((ext_vector_type(8))) short s16x8;
typedef __attribute__((ext_vector_type(4))) short s16x4;
typedef __attribute__((ext_vector_type(4))) float f4v;

__device__ __forceinline__ float bf2f(short u) {
    union { unsigned int i; float f; } v;
    v.i = ((unsigned int)(u16)u) << 16;
    return v.f;
}
__device__ __forceinline__ u16 f2bf(float f) {
    union { float f; unsigned int i; } v; v.f = f;
    unsigned int x = v.i;
    return (u16)((x + 0x7FFFu + ((x >> 16) & 1u)) >> 16);
}

// ---------------- device-wide barrier (monotonic counter, 256 blocks, 1 wave/block) ----------------
__device__ __forceinline__ void grid_barrier(unsigned* bar, unsigned target) {
    __threadfence();                       // release: make this block's writes visible device-wide
    if (threadIdx.x == 0)
        __hip_atomic_fetch_add(bar, 1u, __ATOMIC_ACQ_REL, __HIP_MEMORY_SCOPE_AGENT);
    int spins = 0;
    while (__hip_atomic_load(bar, __ATOMIC_ACQUIRE, __HIP_MEMORY_SCOPE_AGENT) < target) {
        __builtin_amdgcn_s_sleep(1);
        if (++spins > (1 << 20)) break;    // bail-out: avoid infinite hang if co-residency fails
    }
    __threadfence();                       // acquire side
}

__global__ void zero_bar(unsigned* p, int n) {
    if ((int)threadIdx.x < n) p[threadIdx.x] = 0;
}

// ---------------- fp32 -> bf16 weight conversion ----------------
__global__ __launch_bounds__(256)
void cvt_bf16v(const float* __restrict__ src, u16* __restrict__ dst, int n4) {
    int i = blockIdx.x * 256 + threadIdx.x;
    int stride = gridDim.x * 256;
    for (; i < n4; i += stride) {
        f4v v = ((const f4v*)src)[i];
        s16x4 o;
#pragma unroll
        for (int j = 0; j < 4; ++j) o[j] = (short)f2bf(v[j]);
        ((s16x4*)dst)[i] = o;
    }
}

// ---------------- layer0 input gates (one dir): xg = x @ W^T + bih, K=75 ----------------
__global__ __launch_bounds__(256)
void xg0_kernel(const float* __restrict__ x,   // [6400][75]
                const float* __restrict__ W,   // [3072][75] (this dir)
                const float* __restrict__ bih, // [3072]
                u16* __restrict__ xg)          // [6400][3072]
{
    const int bt0 = blockIdx.x * 16;
    __shared__ float xl[16][76];
    for (int idx = threadIdx.x; idx < 16 * 75; idx += 256) {
        int r = idx / 75, k = idx % 75;
        xl[r][k] = x[(size_t)(bt0 + r) * 75 + k];
    }
    __syncthreads();
    for (int i = 0; i < 12; ++i) {
        int g = threadIdx.x + i * 256;
        const float* wr = W + (size_t)g * 75;
        float bv = bih[g];
        float acc[16];
#pragma unroll
        for (int r = 0; r < 16; ++r) acc[r] = bv;
        for (int k = 0; k < 75; ++k) {
            float w = wr[k];
#pragma unroll
            for (int r = 0; r < 16; ++r) acc[r] += xl[r][k] * w;
        }
#pragma unroll
        for (int r = 0; r < 16; ++r)
            xg[(size_t)(bt0 + r) * 3072 + g] = f2bf(acc[r]);
    }
}

// ---------------- MFMA bt-GEMM: C[6400,3072] = A(bf16)[6400,K] @ B(fp32)[3072,K]^T + bias ----------------
__global__ __launch_bounds__(256)
void xg_gemm(const u16* __restrict__ A, const float* __restrict__ Bm,
             const float* __restrict__ bias, u16* __restrict__ C, int K)
{
    __shared__ u16 Alds[64 * 40];
    __shared__ u16 Blds[64 * 40];
    const int m0 = blockIdx.x * 64;
    const int n0 = blockIdx.y * 64;
    const int wave = threadIdx.x >> 6;
    const int lane = threadIdx.x & 63;
    const int r = threadIdx.x >> 2;
    const int kk = (threadIdx.x & 3) * 8;
    const int mrow = wave * 16 + (lane & 15);
    const int kq = (lane >> 4) * 8;
    f4v acc[4];
#pragma unroll
    for (int nt = 0; nt < 4; ++nt) acc[nt] = (f4v){0.f, 0.f, 0.f, 0.f};

    for (int k0 = 0; k0 < K; k0 += 32) {
        *(s16x8*)&Alds[r * 40 + kk] = *(const s16x8*)(A + (size_t)(m0 + r) * K + k0 + kk);
        f4v b0v = *(const f4v*)(Bm + (size_t)(n0 + r) * K + k0 + kk);
        f4v b1v = *(const f4v*)(Bm + (size_t)(n0 + r) * K + k0 + kk + 4);
        s16x8 bb;
#pragma unroll
        for (int i = 0; i < 4; ++i) { bb[i] = (short)f2bf(b0v[i]); bb[4 + i] = (short)f2bf(b1v[i]); }
        *(s16x8*)&Blds[r * 40 + kk] = bb;
        __syncthreads();
        s16x8 a = *(const s16x8*)&Alds[mrow * 40 + kq];
#pragma unroll
        for (int nt = 0; nt < 4; ++nt) {
            s16x8 b = *(const s16x8*)&Blds[(nt * 16 + (lane & 15)) * 40 + kq];
            acc[nt] = __builtin_amdgcn_mfma_f32_16x16x32_bf16(a, b, acc[nt], 0, 0, 0);
        }
        __syncthreads();
    }
    const int col = lane & 15;
    const int rq = (lane >> 4) * 4;
#pragma unroll
    for (int nt = 0; nt < 4; ++nt) {
        int n = n0 + nt * 16 + col;
        float bbv = bias[n];
#pragma unroll
        for (int rg = 0; rg < 4; ++rg) {
            int m = m0 + wave * 16 + rq + rg;
            C[(size_t)m * 3072 + n] = f2bf(acc[nt][rg] + bbv);
        }
    }
}

// ---------------- persistent encoder layer scan (one dir), MFMA recurrent GEMM ----------------
// 256 blocks x 64 threads. block = (j-slice of 16, m-quarter of 16 batches).
__global__ __launch_bounds__(64)
void enc_persist(const u16* __restrict__ W,      // [3072][1024] bf16 (this dir)
                 const float* __restrict__ bias, // [2][3072] (bih,bhh) this dir
                 const u16* __restrict__ xg,     // [6400][3072] bf16 this dir
                 float* __restrict__ h32,        // [2][64][1024] fp32 ping-pong
                 u16* __restrict__ hbf,          // [2][64][1024] bf16 ping-pong
                 u16* __restrict__ y,            // [6400][2048] bf16
                 int dir, unsigned* __restrict__ bar)
{
    const int lane = threadIdx.x;
    const int j0 = (blockIdx.x >> 2) * 16;
    const int b0 = (blockIdx.x & 3) * 16;
    const int jc = j0 + (lane & 15);
    const int kq = (lane >> 4) * 8;
    const float bhr = bias[3072 + jc];
    const float bhz = bias[4096 + jc];
    const float bhn = bias[5120 + jc];
    const u16* wR = W + (size_t)jc * 1024 + kq;
    const u16* wZ = W + (size_t)(1024 + jc) * 1024 + kq;
    const u16* wN = W + (size_t)(2048 + jc) * 1024 + kq;
    const int brow = b0 + (lane >> 4) * 4;

    for (int t = 0; t < 100; ++t) {
        f4v aR = {0.f, 0.f, 0.f, 0.f}, aZ = aR, aN = aR;
        if (t > 0) {
            const u16* hb = hbf + (size_t)(t & 1) * 65536
                          + (size_t)(b0 + (lane & 15)) * 1024 + kq;
            for (int k0 = 0; k0 < 1024; k0 += 32) {
                s16x8 av = *(const s16x8*)(hb + k0);
                s16x8 vR = *(const s16x8*)(wR + k0);
                s16x8 vZ = *(const s16x8*)(wZ + k0);
                s16x8 vN = *(const s16x8*)(wN + k0);
                aR = __builtin_amdgcn_mfma_f32_16x16x32_bf16(av, vR, aR, 0, 0, 0);
                aZ = __builtin_amdgcn_mfma_f32_16x16x32_bf16(av, vZ, aZ, 0, 0, 0);
                aN = __builtin_amdgcn_mfma_f32_16x16x32_bf16(av, vN, aN, 0, 0, 0);
            }
        }
        const float* h32r = h32 + (size_t)(t & 1) * 65536;
        float* h32w = h32 + (size_t)((t + 1) & 1) * 65536;
        u16*   hbw  = hbf + (size_t)((t + 1) & 1) * 65536;
#pragma unroll
        for (int r = 0; r < 4; ++r) {
            int b = brow + r;
            const u16* xr = xg + ((size_t)b * 100 + t) * 3072;
            float pr = bf2f((short)xr[jc]) + aR[r] + bhr;
            float pz = bf2f((short)xr[1024 + jc]) + aZ[r] + bhz;
            float pn = bf2f((short)xr[2048 + jc]);
            float hold = (t > 0) ? h32r[(size_t)b * 1024 + jc] : 0.f;
            float rg = 1.f / (1.f + expf(-pr));
            float zg = 1.f / (1.f + expf(-pz));
            float ng = tanhf(pn + rg * (aN[r] + bhn));
            float hnew = (1.f - zg) * ng + zg * hold;
            h32w[(size_t)b * 1024 + jc] = hnew;
            hbw[(size_t)b * 1024 + jc] = f2bf(hnew);
            y[((size_t)b * 100 + t) * 2048 + dir * 1024 + jc] = f2bf(hnew);
        }
        if (t < 99) grid_barrier(bar, 256u * (unsigned)(t + 1));
    }
}

// ---------------- persistent decoder scan, H=K=2048, input gates = biases only ----------------
// 256 blocks x 64 threads. block = (j-slice of 16, m-half of 32 batches).
__global__ __launch_bounds__(64)
void dec_persist(const u16* __restrict__ W,     // [6144][2048] bf16
                 const float* __restrict__ db,  // [2][6144] fp32
                 float* __restrict__ h32,       // [2][64][2048] fp32 ping-pong
                 u16* __restrict__ hbf,         // [2][64][2048] bf16 ping-pong
                 u16* __restrict__ ys,          // [6400][2048] bf16
                 unsigned* __restrict__ bar)
{
    const int lane = threadIdx.x;
    const int j0 = (blockIdx.x >> 1) * 16;
    const int b0 = (blockIdx.x & 1) * 32;
    const int jc = j0 + (lane & 15);
    const int kq = (lane >> 4) * 8;
    const float gir = db[jc]        + db[6144 + jc];
    const float giz = db[2048 + jc] + db[8192 + jc];
    const float gin = db[4096 + jc];
    const float bhn = db[10240 + jc];
    const u16* wR = W + (size_t)jc * 2048 + kq;
    const u16* wZ = W + (size_t)(2048 + jc) * 2048 + kq;
    const u16* wN = W + (size_t)(4096 + jc) * 2048 + kq;

    for (int t = 0; t < 100; ++t) {
        f4v aR[2], aZ[2], aN[2];
#pragma unroll
        for (int mt = 0; mt < 2; ++mt) {
            aR[mt] = (f4v){0.f, 0.f, 0.f, 0.f}; aZ[mt] = aR[mt]; aN[mt] = aR[mt];
        }
        const u16* hbase = hbf + (size_t)(t & 1) * 131072;
        for (int k0 = 0; k0 < 2048; k0 += 32) {
            s16x8 vR = *(const s16x8*)(wR + k0);
            s16x8 vZ = *(const s16x8*)(wZ + k0);
            s16x8 vN = *(const s16x8*)(wN + k0);
#pragma unroll
            for (int mt = 0; mt < 2; ++mt) {
                s16x8 av = *(const s16x8*)(hbase
                    + (size_t)(b0 + mt * 16 + (lane & 15)) * 2048 + kq + k0);
                aR[mt] = __builtin_amdgcn_mfma_f32_16x16x32_bf16(av, vR, aR[mt], 0, 0, 0);
                aZ[mt] = __builtin_amdgcn_mfma_f32_16x16x32_bf16(av, vZ, aZ[mt], 0, 0, 0);
                aN[mt] = __builtin_amdgcn_mfma_f32_16x16x32_bf16(av, vN, aN[mt], 0, 0, 0);
            }
        }
        const float* h32r = h32 + (size_t)(t & 1) * 131072;
        float* h32w = h32 + (size_t)((t + 1) & 1) * 131072;
        u16*   hbw  = hbf + (size_t)((t + 1) & 1) * 131072;
#pragma unroll
        for (int mt = 0; mt < 2; ++mt) {
#pragma unroll
            for (int r = 0; r < 4; ++r) {
                int b = b0 + mt * 16 + (lane >> 4) * 4 + r;
                float pr = gir + aR[mt][r];
                float pz = giz + aZ[mt][r];
                float rg = 1.f / (1.f + expf(-pr));
                float zg = 1.f / (1.f + expf(-pz));
                float ng = tanhf(gin + rg * (aN[mt][r] + bhn));
                float hold = h32r[(size_t)b * 2048 + jc];
                float hnew = (1.f - zg) * ng + zg * hold;
                h32w[(size_t)b * 2048 + jc] = hnew;
                hbw[(size_t)b * 2048 + jc] = f2bf(hnew);
                ys[((size_t)b * 100 + t) * 2048 + jc] = f2bf(hnew);
            }
        }
        if (t < 99) grid_barrier(bar, 256u * (unsigned)(t + 1));
    }
}

// ---------------- gather enc_hidden = y[b, sl-1]; init decoder h ----------------
__global__ __launch_bounds__(256)
void gather_kernel(const int* __restrict__ seq_len, const u16* __restrict__ y,
                   float* __restrict__ out_enc, float* __restrict__ h32d,
                   u16* __restrict__ hbfd)
{
    int idx = blockIdx.x * 256 + threadIdx.x;   // < 131072
    int b = idx >> 11, j = idx & 2047;
    int s = seq_len[b];
    s = s < 1 ? 1 : (s > 100 ? 100 : s);
    u16 v = y[((size_t)b * 100 + (s - 1)) * 2048 + j];
    float f = bf2f((short)v);
    out_enc[idx] = f;
    h32d[idx] = f;     // pp0
    hbfd[idx] = v;     // pp0
}

// ---------------- output projection: dec_out[6400,75] = ys @ out_W^T + out_b ----------------
__global__ __launch_bounds__(256)
void proj_kernel(const u16* __restrict__ ys, const float* __restrict__ oW,
                 const float* __restrict__ oB, float* __restrict__ dec_out)
{
    const int r0 = blockIdx.x * 8;   // 800 blocks
    __shared__ float yl[8][2048];
    __shared__ float psum[3][8][76];
    for (int idx = threadIdx.x; idx < 2048; idx += 256) {
        int rr = idx >> 8, cc = idx & 255;
        s16x8 v = ((const s16x8*)(ys + (size_t)(r0 + rr) * 2048))[cc];
#pragma unroll
        for (int i = 0; i < 8; ++i) yl[rr][cc * 8 + i] = bf2f(v[i]);
    }
    __syncthreads();
    if (threadIdx.x < 225) {
        int d = threadIdx.x % 75, seg = threadIdx.x / 75;
        int ks = seg * 683, ke = ks + 683 < 2048 ? ks + 683 : 2048;
        const float* wr = oW + (size_t)d * 2048;
        float acc[8] = {0.f, 0.f, 0.f, 0.f, 0.f, 0.f, 0.f, 0.f};
        for (int k = ks; k < ke; ++k) {
            float w = wr[k];
#pragma unroll
            for (int r = 0; r < 8; ++r) acc[r] += yl[r][k] * w;
        }
#pragma unroll
        for (int r = 0; r < 8; ++r) psum[seg][r][d] = acc[r];
    }
    __syncthreads();
    for (int idx = threadIdx.x; idx < 600; idx += 256) {
        int r = idx / 75, d = idx % 75;
        dec_out[(size_t)(r0 + r) * 75 + d] =
            psum[0][r][d] + psum[1][r][d] + psum[2][r][d] + oB[d];
    }
}

// ================== round-3 fallback kernels (small-ws path) ==================
__device__ __forceinline__ void gemv3_f32(const float* __restrict__ w0,
                                          const float* __restrict__ w1,
                                          const float* __restrict__ w2,
                                          const f4v* __restrict__ hv,
                                          int n4, float& a0, float& a1, float& a2)
{
    for (int k = 0; k < n4; ++k) {
        f4v h4 = hv[k];
        f4v x0 = *(const f4v*)(w0 + k * 4);
        f4v x1 = *(const f4v*)(w1 + k * 4);
        f4v x2 = *(const f4v*)(w2 + k * 4);
        a0 += h4[0]*x0[0] + h4[1]*x0[1] + h4[2]*x0[2] + h4[3]*x0[3];
        a1 += h4[0]*x1[0] + h4[1]*x1[1] + h4[2]*x1[2] + h4[3]*x1[3];
        a2 += h4[0]*x2[0] + h4[1]*x2[1] + h4[2]*x2[2] + h4[3]*x2[3];
    }
}
__device__ __forceinline__ float dot_w32_v32(const float* __restrict__ w,
                                             const float* __restrict__ v, int n)
{
    float a = 0.f;
    for (int k = 0; k < n; ++k) a += w[k] * v[k];
    return a;
}
__device__ __forceinline__ float dot_w32_vbf(const float* __restrict__ w,
                                             const u16* __restrict__ v, int n8)
{
    float a = 0.f;
    for (int k8 = 0; k8 < n8; ++k8) {
        s16x8 v8 = *(const s16x8*)(v + k8 * 8);
        f4v w0 = *(const f4v*)(w + k8 * 8);
        f4v w1 = *(const f4v*)(w + k8 * 8 + 4);
        a += w0[0]*bf2f(v8[0]) + w0[1]*bf2f(v8[1]) + w0[2]*bf2f(v8[2]) + w0[3]*bf2f(v8[3])
           + w1[0]*bf2f(v8[4]) + w1[1]*bf2f(v8[5]) + w1[2]*bf2f(v8[6]) + w1[3]*bf2f(v8[7]);
    }
    return a;
}

__global__ __launch_bounds__(512)
void enc_scan_fused(int t,
                    const float* __restrict__ h_in, float* __restrict__ h_out,
                    const float* __restrict__ Whh, size_t whh_stride,
                    const float* __restrict__ Wih, size_t wih_stride, int Kin,
                    const float* __restrict__ xf, const u16* __restrict__ xb,
                    const float* __restrict__ bias, int bias_stride,
                    u16* __restrict__ y)
{
    const int dir = blockIdx.z;
    const int jt = blockIdx.x;
    const int b0 = blockIdx.y * 16;
    __shared__ float hlds[16][1024];
    const float* hin = h_in + (size_t)dir * 65536 + (size_t)b0 * 1024;
    if (t == 0) {
        f4v z = {0.f, 0.f, 0.f, 0.f};
        for (int idx = threadIdx.x; idx < 4096; idx += 512) ((f4v*)hlds)[idx] = z;
    } else {
        for (int idx = threadIdx.x; idx < 4096; idx += 512)
            ((f4v*)hlds)[idx] = ((const f4v*)hin)[idx];
    }
    __syncthreads();
    const int jl = threadIdx.x & 31;
    const int j  = jt * 32 + jl;
    const int bp = threadIdx.x >> 5;
    const float* wd = Whh + (size_t)dir * whh_stride;
    float a0 = 0.f, a1 = 0.f, a2 = 0.f;
    gemv3_f32(wd + (size_t)j * 1024, wd + (size_t)(1024 + j) * 1024,
              wd + (size_t)(2048 + j) * 1024, (const f4v*)&hlds[bp][0], 256, a0, a1, a2);
    const float* bd = bias + dir * bias_stride;
    const float* wi = Wih + (size_t)dir * wih_stride;
    const int gb = b0 + bp;
    float gi[3];
#pragma unroll
    for (int g = 0; g < 3; ++g) {
        const float* wr = wi + (size_t)(g * 1024 + j) * Kin;
        float s;
        if (xf) s = dot_w32_v32(wr, xf + ((size_t)gb * 100 + t) * Kin, Kin);
        else    s = dot_w32_vbf(wr, xb + ((size_t)gb * 100 + t) * Kin, Kin >> 3);
        gi[g] = bd[g * 1024 + j] + s;
    }
    const float* bhh = bd + 3072;
    float pr = gi[0] + a0 + bhh[j];
    float pz = gi[1] + a1 + bhh[1024 + j];
    float rg = 1.f / (1.f + expf(-pr));
    float zg = 1.f / (1.f + expf(-pz));
    float ng = tanhf(gi[2] + rg * (a2 + bhh[2048 + j]));
    float hold = hlds[bp][j];
    float hnew = (1.f - zg) * ng + zg * hold;
    h_out[(size_t)dir * 65536 + (size_t)gb * 1024 + j] = hnew;
    y[((size_t)gb * 100 + t) * 2048 + (size_t)dir * 1024 + j] = f2bf(hnew);
}

__global__ __launch_bounds__(512)
void dec_scan_step(int t, const float* __restrict__ h_in, float* __restrict__ h_out,
                   const float* __restrict__ Whh, const float* __restrict__ db,
                   u16* __restrict__ ys)
{
    const int jt = blockIdx.x;
    const int b0 = blockIdx.y * 16;
    __shared__ float hlds[16][1024];
    const int jl = threadIdx.x & 31;
    const int j  = jt * 32 + jl;
    const int bp = threadIdx.x >> 5;
    float a0 = 0.f, a1 = 0.f, a2 = 0.f;
    float hold = 0.f;
    for (int kc = 0; kc < 2; ++kc) {
        for (int idx = threadIdx.x; idx < 4096; idx += 512) {
            int rr = idx >> 8, cc = idx & 255;
            ((f4v*)hlds)[idx] = *(const f4v*)(h_in + (size_t)(b0 + rr) * 2048 + kc * 1024 + cc * 4);
        }
        __syncthreads();
        if ((j >> 10) == kc) hold = hlds[bp][j & 1023];
        const float* wb = Whh + kc * 1024;
        gemv3_f32(wb + (size_t)j * 2048, wb + (size_t)(2048 + j) * 2048,
                  wb + (size_t)(4096 + j) * 2048, (const f4v*)&hlds[bp][0], 256, a0, a1, a2);
        __syncthreads();
    }
    const int gb = b0 + bp;
    float pr = db[j] + a0 + db[6144 + j];
    float pz = db[2048 + j] + a1 + db[6144 + 2048 + j];
    float rg = 1.f / (1.f + expf(-pr));
    float zg = 1.f / (1.f + expf(-pz));
    float ng = tanhf(db[4096 + j] + rg * (a2 + db[6144 + 4096 + j]));
    float hnew = (1.f - zg) * ng + zg * hold;
    h_out[(size_t)gb * 2048 + j] = hnew;
    ys[((size_t)gb * 100 + t) * 2048 + j] = f2bf(hnew);
}

// ============================ launcher ============================
extern "C" void kernel_launch(void* const* d_in, const int* in_sizes, int n_in,
                              void* d_out, int out_size, void* d_ws, size_t ws_size,
                              hipStream_t stream)
{
    const float* x    = (const float*)d_in[0];
    const int*   sl   = (const int*)d_in[1];
    const float* Wih0 = (const float*)d_in[2];
    const float* Whh0 = (const float*)d_in[3];
    const float* b0   = (const float*)d_in[4];
    const float* Wih  = (const float*)d_in[5];
    const float* Whh  = (const float*)d_in[6];
    const float* bE   = (const float*)d_in[7];
    const float* dWhh = (const float*)d_in[9];
    const float* dB   = (const float*)d_in[10];
    const float* oW   = (const float*)d_in[11];
    const float* oB   = (const float*)d_in[12];
    float* out_enc = (float*)d_out;            // [64][2048]
    float* dec_out = (float*)d_out + 131072;   // [64][100][75]

    char* ws = (char*)d_ws;
    // ---- persistent-path layout (95.75 MiB) ----
    const size_t XG_OFF   = 0;            // [6400][3072] bf16 (one dir): 39,321,600
    const size_t YA_OFF   = 39321600;     // [6400][2048] bf16: 26,214,400
    const size_t YB_OFF   = 65536000;     // [6400][2048] bf16
    const size_t WC_OFF   = 91750400;     // [3072][1024] bf16: 6,291,456
    const size_t H32E_OFF = 98041856;     // [2][64][1024] f32: 524,288
    const size_t HBFE_OFF = 98566144;     // [2][64][1024] bf16: 262,144
    const size_t H32D_OFF = 98828288;     // [2][64][2048] f32: 1,048,576
    const size_t HBFD_OFF = 99876864;     // [2][64][2048] bf16: 524,288
    const size_t BAR_OFF  = 100401152;    // 256 B
    const size_t NEED     = 100401408;

    dim3 blk256(256), blk512(512), blk64(64);

    if (ws_size >= NEED) {
        u16*   xg   = (u16*)(ws + XG_OFF);
        u16*   y_a  = (u16*)(ws + YA_OFF);
        u16*   y_b  = (u16*)(ws + YB_OFF);
        u16*   Wc   = (u16*)(ws + WC_OFF);
        float* h32E = (float*)(ws + H32E_OFF);
        u16*   hbfE = (u16*)(ws + HBFE_OFF);
        float* h32D = (float*)(ws + H32D_OFF);
        u16*   hbfD = (u16*)(ws + HBFD_OFF);
        unsigned* bar = (unsigned*)(ws + BAR_OFF);

        zero_bar<<<1, 64, 0, stream>>>(bar, 16);

        int slot = 0;
        for (int l = 0; l < 3; ++l) {
            const u16* y_in = (l == 0) ? (const u16*)0 : ((l == 1) ? y_a : y_b);
            u16* y_out      = (l == 2) ? y_a : ((l == 0) ? y_a : y_b);
            for (int d = 0; d < 2; ++d) {
                const float* Wsrc = (l == 0) ? (Whh0 + (size_t)d * 3145728)
                                             : (Whh + ((size_t)(l - 1) * 2 + d) * 3145728);
                const float* bias = (l == 0) ? (b0 + (size_t)d * 6144)
                                             : (bE + (size_t)(l - 1) * 12288 + (size_t)d * 6144);
                cvt_bf16v<<<dim3(1024), blk256, 0, stream>>>(Wsrc, Wc, 786432);
                if (l == 0)
                    xg0_kernel<<<dim3(400), blk256, 0, stream>>>(
                        x, Wih0 + (size_t)d * 230400, b0 + (size_t)d * 6144, xg);
                else
                    xg_gemm<<<dim3(100, 48), blk256, 0, stream>>>(
                        y_in, Wih + ((size_t)(l - 1) * 2 + d) * 6291456, bias, xg, 2048);
                enc_persist<<<dim3(256), blk64, 0, stream>>>(
                    Wc, bias, xg, h32E, hbfE, y_out, d, bar + slot);
                ++slot;
            }
        }
        gather_kernel<<<dim3(512), blk256, 0, stream>>>(sl, y_a, out_enc, h32D, hbfD);
        u16* decW = (u16*)(ws + XG_OFF);   // reuse xg region (25.2 MB needed)
        cvt_bf16v<<<dim3(2048), blk256, 0, stream>>>(dWhh, decW, 3145728);
        dec_persist<<<dim3(256), blk64, 0, stream>>>(decW, dB, h32D, hbfD, y_b, bar + 6);
        proj_kernel<<<dim3(800), blk256, 0, stream>>>(y_b, oW, oB, dec_out);
    } else {
        // ---- fallback: round-3 fused path (~55 MiB) ----
        const size_t Y_B = 26214400;
        u16*   y_a  = (u16*)ws;
        u16*   y_b  = (u16*)(ws + Y_B);
        float* hE   = (float*)(ws + 2 * Y_B);                 // [2][2][64][1024] f32: 1 MB
        float* h32D = (float*)(ws + 2 * Y_B + 1048576);       // [2][64][2048] f32: 1 MB
        u16*   hbfD = (u16*)(ws + 2 * Y_B + 2097152);         // 0.5 MB

        for (int t = 0; t < 100; ++t) {
            int pp = t & 1;
            enc_scan_fused<<<dim3(32, 4, 2), blk512, 0, stream>>>(
                t, hE + (size_t)pp * 131072, hE + (size_t)(pp ^ 1) * 131072,
                Whh0, (size_t)3145728, Wih0, (size_t)230400, 75, x, (const u16*)0,
                b0, 6144, y_a);
        }
        for (int l = 0; l < 2; ++l) {
            const u16* yin = (l == 0) ? y_a : y_b;
            u16* yout      = (l == 0) ? y_b : y_a;
            for (int t = 0; t < 100; ++t) {
                int pp = t & 1;
                enc_scan_fused<<<dim3(32, 4, 2), blk512, 0, stream>>>(
                    t, hE + (size_t)pp * 131072, hE + (size_t)(pp ^ 1) * 131072,
                    Whh + (size_t)l * 2 * 3145728, (size_t)3145728,
                    Wih + (size_t)l * 2 * 6291456, (size_t)6291456, 2048,
                    (const float*)0, yin, bE + (size_t)l * 12288, 6144, yout);
            }
        }
        gather_kernel<<<dim3(512), blk256, 0, stream>>>(sl, y_a, out_enc, h32D, hbfD);
        for (int t = 0; t < 100; ++t) {
            int pp = t & 1;
            dec_scan_step<<<dim3(64, 4), blk512, 0, stream>>>(
                t, h32D + (size_t)pp * 131072, h32D + (size_t)(pp ^ 1) * 131072, dWhh, dB, y_b);
        }
        proj_kernel<<<dim3(800), blk256, 0, stream>>>(y_b, oW, oB, dec_out);
    }
}